// Round 3
// baseline (12902.504 us; speedup 1.0000x reference)
//
#include <hip/hip_runtime.h>
#include <hip/hip_bf16.h>

typedef unsigned short u16;
typedef unsigned int u32;
typedef unsigned long long u64;
typedef short s8v __attribute__((ext_vector_type(8)));
typedef float f4v __attribute__((ext_vector_type(4)));
typedef u32 u32x4 __attribute__((ext_vector_type(4)));

#define BQ 32
#define TQ 512
#define DQ 1024
#define CHUNK 128
#define NCHUNK (TQ / CHUNK)
#define NTHR 256
#define NBLK_R 256

__device__ __host__ inline u16 f2bf(float f) {
    union { float f; unsigned u; } v; v.f = f;
    unsigned r = v.u + 0x7fffu + ((v.u >> 16) & 1u);  // RNE
    return (u16)(r >> 16);
}
__device__ __host__ inline float bf2f(u16 u) {
    union { unsigned u; float f; } v; v.u = ((unsigned)u) << 16;
    return v.f;
}

// Zero hh slot 0 and the state/counter span.
__global__ void init_kernel(u32* __restrict__ z0, size_t n0,
                            u32* __restrict__ z1, size_t n1) {
    size_t i = (size_t)blockIdx.x * blockDim.x + threadIdx.x;
    size_t stride = (size_t)gridDim.x * blockDim.x;
    for (size_t idx = i; idx < n0; idx += stride) z0[idx] = 0;
    for (size_t idx = i; idx < n1; idx += stride) z1[idx] = 0;
}

// Unpack 8 packed (hi<<16|lo) u32 cols into hi/lo bf16x8 fragments.
__device__ inline void unpack_pk(u32x4 A, u32x4 B, s8v& hi, s8v& lo) {
    union { u32 u[4]; s8v v; } H, L;
    H.u[0] = (A[0] >> 16) | (A[1] & 0xffff0000u); L.u[0] = (A[0] & 0xffffu) | (A[1] << 16);
    H.u[1] = (A[2] >> 16) | (A[3] & 0xffff0000u); L.u[1] = (A[2] & 0xffffu) | (A[3] << 16);
    H.u[2] = (B[0] >> 16) | (B[1] & 0xffff0000u); L.u[2] = (B[0] & 0xffffu) | (B[1] << 16);
    H.u[3] = (B[2] >> 16) | (B[3] & 0xffff0000u); L.u[3] = (B[2] & 0xffffu) | (B[3] << 16);
    hi = H.v; lo = L.v;
}

// ---------------------------------------------------------------------------
// xproj GEMM: unchanged (verified).
// ---------------------------------------------------------------------------
__global__ __launch_bounds__(NTHR) void xproj_gemm_kernel(
    const float* __restrict__ in_f32,   // layer0, or null
    const u32* __restrict__ hh,         // [T+1][BQ][DQ] packed hi|lo (layer1)
    const int* __restrict__ lens,
    const float* __restrict__ W,        // [2048][4096], rows [0,1024) used
    const float* __restrict__ bias,     // [4096]
    float* __restrict__ zx,             // [B*CHUNK][4096]
    int t0)
{
    __shared__ u16 As[2][128][40];
    __shared__ u16 Bs[2][128][40];

    const int tid = threadIdx.x;
    const int bm = blockIdx.x & 31;
    const int bn = blockIdx.x >> 5;

    const int wv = tid >> 6;
    const int wm = wv >> 1, wn = wv & 1;
    const int lane = tid & 63;
    const int frow = lane & 15;
    const int quad = lane >> 4;

    const int am = tid >> 1;
    const int akh = (tid & 1) * 16;
    const int amg = bm * 128 + am;
    const int ab = amg >> 7;            // batch
    const int atl = amg & 127;          // t within chunk
    const int at = t0 + atl;

    const int bk = tid >> 3;
    const int bng = (tid & 7) * 16;

    bool arow_live = true;
    size_t arow;
    if (in_f32) {
        arow = ((size_t)ab * TQ + at) * DQ;
    } else {
        arow = ((size_t)(at + 1) * BQ + ab) * DQ;   // hh slot at+1 holds h_at
        arow_live = (at < lens[ab]);
    }

    f4v acc[4][4];
    #pragma unroll
    for (int i = 0; i < 4; ++i)
        #pragma unroll
        for (int j = 0; j < 4; ++j) acc[i][j] = (f4v){0.f, 0.f, 0.f, 0.f};

    for (int kt = 0; kt < 32; ++kt) {
        const int k0 = kt * 32;
        if (in_f32) {
            const float* src = in_f32 + arow + k0 + akh;
            #pragma unroll
            for (int j4 = 0; j4 < 4; ++j4) {
                float4 v = ((const float4*)src)[j4];
                float vv[4] = {v.x, v.y, v.z, v.w};
                #pragma unroll
                for (int e = 0; e < 4; ++e) {
                    u16 hh16 = f2bf(vv[e]);
                    As[0][am][akh + j4 * 4 + e] = hh16;
                    As[1][am][akh + j4 * 4 + e] = f2bf(vv[e] - bf2f(hh16));
                }
            }
        } else {
            const u32* src = hh + arow + k0 + akh;
            #pragma unroll
            for (int j4 = 0; j4 < 4; ++j4) {
                uint4 v = ((const uint4*)src)[j4];
                if (!arow_live) { v.x = v.y = v.z = v.w = 0; }
                u32 vv[4] = {v.x, v.y, v.z, v.w};
                #pragma unroll
                for (int e = 0; e < 4; ++e) {
                    As[0][am][akh + j4 * 4 + e] = (u16)(vv[e] >> 16);
                    As[1][am][akh + j4 * 4 + e] = (u16)(vv[e] & 0xffffu);
                }
            }
        }
        {
            const float* wsrc = W + (size_t)(k0 + bk) * (4 * DQ) + bn * 128 + bng;
            #pragma unroll
            for (int j4 = 0; j4 < 4; ++j4) {
                float4 v = ((const float4*)wsrc)[j4];
                float vv[4] = {v.x, v.y, v.z, v.w};
                #pragma unroll
                for (int e = 0; e < 4; ++e) {
                    u16 hh16 = f2bf(vv[e]);
                    int n = bng + j4 * 4 + e;
                    Bs[0][n][bk] = hh16;
                    Bs[1][n][bk] = f2bf(vv[e] - bf2f(hh16));
                }
            }
        }
        __syncthreads();

        s8v ah[4], al[4], bh[4], bl[4];
        #pragma unroll
        for (int mt = 0; mt < 4; ++mt) {
            ah[mt] = *(const s8v*)&As[0][wm * 64 + mt * 16 + frow][quad * 8];
            al[mt] = *(const s8v*)&As[1][wm * 64 + mt * 16 + frow][quad * 8];
        }
        #pragma unroll
        for (int nt = 0; nt < 4; ++nt) {
            bh[nt] = *(const s8v*)&Bs[0][wn * 64 + nt * 16 + frow][quad * 8];
            bl[nt] = *(const s8v*)&Bs[1][wn * 64 + nt * 16 + frow][quad * 8];
        }
        #pragma unroll
        for (int mt = 0; mt < 4; ++mt)
            #pragma unroll
            for (int nt = 0; nt < 4; ++nt) {
                acc[mt][nt] = __builtin_amdgcn_mfma_f32_16x16x32_bf16(ah[mt], bh[nt], acc[mt][nt], 0, 0, 0);
                acc[mt][nt] = __builtin_amdgcn_mfma_f32_16x16x32_bf16(al[mt], bh[nt], acc[mt][nt], 0, 0, 0);
                acc[mt][nt] = __builtin_amdgcn_mfma_f32_16x16x32_bf16(ah[mt], bl[nt], acc[mt][nt], 0, 0, 0);
            }
        __syncthreads();
    }

    float bv[4];
    #pragma unroll
    for (int nt = 0; nt < 4; ++nt) bv[nt] = bias[bn * 128 + wn * 64 + nt * 16 + frow];
    #pragma unroll
    for (int mt = 0; mt < 4; ++mt) {
        #pragma unroll
        for (int nt = 0; nt < 4; ++nt) {
            int col = bn * 128 + wn * 64 + nt * 16 + frow;
            #pragma unroll
            for (int r = 0; r < 4; ++r) {
                int row = bm * 128 + wm * 64 + mt * 16 + quad * 4 + r;
                zx[(size_t)row * (4 * DQ) + col] = acc[mt][nt][r] + bv[nt];
            }
        }
    }
}

// ---------------------------------------------------------------------------
// Recurrence: round-0 topology (256 blocks = 2 halves x 128 col-groups,
// halves on XCD parity), with a shortened per-step latency chain:
//  - arrival: fire-and-forget atomicAdd per (t, half, K-quarter), one add per
//    producer wave (waves 0,1) after its OWN vmcnt drain (no block sync).
//  - wait: per-WAVE poll of its own K-quarter counter (fan-in 64 = 32 blocks
//    x 2 waves); wave proceeds to its h-loads + MFMA without waiting for
//    other quarters -- quarter skew overlaps with early waves' compute.
//  - red[] parity double-buffered => single __syncthreads per step.
// ---------------------------------------------------------------------------
__global__ __launch_bounds__(NTHR, 1) void lstm_rec_kernel(
    const float* __restrict__ zx,   // [B*CHUNK][4096], bias folded in
    const float* __restrict__ W,    // [2048][4096], rows [1024,2048) used
    const int* __restrict__ lens,
    u32* __restrict__ hh,           // [T+1][BQ][DQ] packed hi|lo
    u32* __restrict__ qc,           // [T][2][4][16] quarter counters
    float* __restrict__ state_h,    // [B*DQ]
    float* __restrict__ state_c,    // [B*DQ]
    float* __restrict__ out_f32,    // layer1: d_out (else null)
    float* __restrict__ hc_out,     // layer1: d_out + B*T*DQ (h1 then c1)
    int t0, int is_last)
{
    __shared__ u16 wt[2][32][1032];
    __shared__ float red[2][4][16][36];   // parity double-buffered

    const int tid = threadIdx.x;
    const int blk = blockIdx.x;
    const int bg = blk & 1;          // batch-half (XCD parity under blk%8)
    const int cg = blk >> 1;         // col-group 0..127 (hcols cg*8 .. +8)
    const int quarter = cg >> 5;     // which K-quarter this block produces

    for (int idx = tid; idx < 32 * 1024; idx += NTHR) {
        int n = idx & 31, k = idx >> 5;
        int c = n >> 2, g = n & 3;
        float w = W[(size_t)(DQ + k) * (4 * DQ) + g * DQ + cg * 8 + c];
        u16 wh = f2bf(w);
        wt[0][n][k] = wh;
        wt[1][n][k] = f2bf(w - bf2f(wh));
    }

    const int gb_l = tid >> 3;       // local batch 0..15
    const int gc = tid & 7;          // local hcol 0..7
    const int b_g = bg * 16 + gb_l;
    const int hcol = cg * 8 + gc;
    float c_state = 0.f, h_state = 0.f;
    int mylen = 0;
    if (tid < 128) {
        mylen = lens[b_g];
        h_state = state_h[(size_t)b_g * DQ + hcol];
        c_state = state_c[(size_t)b_g * DQ + hcol];
    }

    const int wave = tid >> 6;
    const int lane = tid & 63;
    const int frow = lane & 15;
    const int quad = lane >> 4;
    const int ksrc = wave * 256;     // K-split across 4 waves

    __syncthreads();

    const int tend = t0 + CHUNK;
    for (int t = t0; t < tend; ++t) {
        // ---- zx prefetch (issued before the poll; overlaps the wait) ----
        float zxv[4];
        if (tid < 128) {
            size_t base = ((size_t)b_g * CHUNK + (t - t0)) * (4 * DQ) + hcol;
            #pragma unroll
            for (int g = 0; g < 4; ++g) zxv[g] = zx[base + (size_t)g * DQ];
        }

        // ---- per-wave wait: my K-quarter of h_{t-1} is fully stored ----
        if (t > t0) {
            const u32* qp = qc + (((size_t)(t - 1) * 2 + bg) * 4 + wave) * 16;
            if (lane == 0) {
                while (__hip_atomic_load(qp, __ATOMIC_RELAXED,
                                         __HIP_MEMORY_SCOPE_AGENT) < 64u) { }
            }
            __builtin_amdgcn_sched_barrier(0);
        }

        // ---- h read: plain cached (fresh addr; per-XCD L2 dedup) ----
        const u32* hp = hh + ((size_t)t * BQ + (bg * 16 + frow)) * DQ + ksrc + quad * 8;
        u32x4 q[16];
        #pragma unroll
        for (int s = 0; s < 8; ++s) {
            q[2 * s]     = *(const u32x4*)(hp + s * 32);
            q[2 * s + 1] = *(const u32x4*)(hp + s * 32 + 4);
        }

        // ---- MFMA: 4 independent chains to hide dep latency ----
        f4v acc0 = {0.f,0.f,0.f,0.f}, acc1 = {0.f,0.f,0.f,0.f};
        f4v acc2 = {0.f,0.f,0.f,0.f}, acc3 = {0.f,0.f,0.f,0.f};
        #pragma unroll
        for (int s = 0; s < 8; ++s) {
            s8v a_h, a_l;
            unpack_pk(q[2 * s], q[2 * s + 1], a_h, a_l);
            const int koff = ksrc + s * 32 + quad * 8;
            s8v b0h = *(const s8v*)&wt[0][frow][koff];
            s8v b0l = *(const s8v*)&wt[1][frow][koff];
            s8v b1h = *(const s8v*)&wt[0][16 + frow][koff];
            s8v b1l = *(const s8v*)&wt[1][16 + frow][koff];
            f4v& A0 = (s & 1) ? acc2 : acc0;
            f4v& A1 = (s & 1) ? acc3 : acc1;
            A0 = __builtin_amdgcn_mfma_f32_16x16x32_bf16(a_h, b0h, A0, 0, 0, 0);
            A1 = __builtin_amdgcn_mfma_f32_16x16x32_bf16(a_h, b1h, A1, 0, 0, 0);
            A0 = __builtin_amdgcn_mfma_f32_16x16x32_bf16(a_l, b0h, A0, 0, 0, 0);
            A1 = __builtin_amdgcn_mfma_f32_16x16x32_bf16(a_l, b1h, A1, 0, 0, 0);
            A0 = __builtin_amdgcn_mfma_f32_16x16x32_bf16(a_h, b0l, A0, 0, 0, 0);
            A1 = __builtin_amdgcn_mfma_f32_16x16x32_bf16(a_h, b1l, A1, 0, 0, 0);
        }
        acc0 += acc2;
        acc1 += acc3;

        const int pb = t & 1;
        #pragma unroll
        for (int r = 0; r < 4; ++r) {
            red[pb][wave][quad * 4 + r][frow] = acc0[r];
            red[pb][wave][quad * 4 + r][16 + frow] = acc1[r];
        }
        __syncthreads();   // the single block-wide realignment per step

        float ho = 0.f;
        size_t oaddr = 0;
        if (tid < 128) {
            float z[4];
            #pragma unroll
            for (int g = 0; g < 4; ++g) {
                int n = gc * 4 + g;
                z[g] = red[pb][0][gb_l][n] + red[pb][1][gb_l][n]
                     + red[pb][2][gb_l][n] + red[pb][3][gb_l][n] + zxv[g];
            }
            float si = 1.f / (1.f + __expf(-z[0]));
            float sf = 1.f / (1.f + __expf(-(z[2] + 1.0f)));  // forget_bias
            float so = 1.f / (1.f + __expf(-z[3]));
            float cn = sf * c_state + si * tanhf(z[1]);
            float hn = so * tanhf(cn);
            bool m = (t < mylen);
            float hk = m ? hn : h_state;
            float ck = m ? cn : c_state;
            h_state = hk; c_state = ck;

            u16 hh16 = f2bf(hk);
            u16 hl16 = f2bf(hk - bf2f(hh16));
            u32 packed = ((u32)hh16 << 16) | (u32)hl16;
            __hip_atomic_store(hh + ((size_t)(t + 1) * BQ + b_g) * DQ + hcol,
                               packed, __ATOMIC_RELAXED, __HIP_MEMORY_SCOPE_AGENT);
            ho = m ? hn : 0.f;
            oaddr = ((size_t)b_g * TQ + t) * DQ + hcol;
        }

        // ---- producer waves: own drain, then fire-and-forget arrival ----
        if (wave < 2 && t < tend - 1) {
            asm volatile("s_waitcnt vmcnt(0)" ::: "memory");
            __builtin_amdgcn_sched_barrier(0);
            if (lane == 0)
                atomicAdd(qc + (((size_t)t * 2 + bg) * 4 + quarter) * 16, 1u);
        }
        // layer-1 output store AFTER the arrive: ack off the critical path
        if (is_last && tid < 128)
            out_f32[oaddr] = ho;
    }

    if (tid < 128) {
        state_h[(size_t)b_g * DQ + hcol] = h_state;
        state_c[(size_t)b_g * DQ + hcol] = c_state;
        if (is_last && tend == TQ) {
            hc_out[(size_t)b_g * DQ + hcol] = h_state;
            hc_out[(size_t)BQ * DQ + (size_t)b_g * DQ + hcol] = c_state;
        }
    }
}

extern "C" void kernel_launch(void* const* d_in, const int* in_sizes, int n_in,
                              void* d_out, int out_size, void* d_ws, size_t ws_size,
                              hipStream_t stream) {
    const float* x    = (const float*)d_in[0];
    const int*   lens = (const int*)d_in[1];
    const float* W0   = (const float*)d_in[2];
    const float* b0   = (const float*)d_in[3];
    const float* W1   = (const float*)d_in[4];
    const float* b1   = (const float*)d_in[5];
    float* out = (float*)d_out;

    const size_t N   = (size_t)BQ * TQ * DQ;           // 16,777,216
    const size_t ZXN = (size_t)BQ * CHUNK * 4 * DQ;    // 16,777,216 f32
    const size_t HD  = (size_t)BQ * DQ;                // 32768
    const size_t QCN = (size_t)TQ * 2 * 4 * 16;        // per-layer counters

    float* zx  = (float*)d_ws;
    u32* hh    = (u32*)(zx + ZXN);                     // [T+1][BQ][DQ]
    // zero span: states + counters (contiguous)
    float* sh0 = (float*)(hh + (size_t)(TQ + 1) * HD);
    float* sc0 = sh0 + HD;
    float* sh1 = sc0 + HD;
    float* sc1 = sh1 + HD;
    u32* qc0   = (u32*)(sc1 + HD);
    u32* qc1   = qc0 + QCN;
    u32* zend  = qc1 + QCN;
    const size_t nzero = (size_t)(zend - (u32*)sh0);

    // zero hh slot 0 (h_{-1} = 0) and the state/counter span
    init_kernel<<<256, 256, 0, stream>>>(hh, HD, (u32*)sh0, nzero);

    for (int c = 0; c < NCHUNK; ++c) {
        int t0 = c * CHUNK;
        xproj_gemm_kernel<<<1024, NTHR, 0, stream>>>(x, nullptr, lens, W0, b0, zx, t0);
        lstm_rec_kernel<<<NBLK_R, NTHR, 0, stream>>>(
            zx, W0, lens, hh, qc0, sh0, sc0,
            nullptr, nullptr, t0, 0);
    }
    for (int c = 0; c < NCHUNK; ++c) {
        int t0 = c * CHUNK;
        xproj_gemm_kernel<<<1024, NTHR, 0, stream>>>(nullptr, hh, lens, W1, b1, zx, t0);
        lstm_rec_kernel<<<NBLK_R, NTHR, 0, stream>>>(
            zx, W1, lens, hh, qc1, sh1, sc1,
            out, out + N, t0, 1);
    }
}

// Round 4
// 6964.952 us; speedup vs baseline: 1.8525x; 1.8525x over previous
//
#include <hip/hip_runtime.h>
#include <hip/hip_bf16.h>

typedef unsigned short u16;
typedef unsigned int u32;
typedef unsigned long long u64;
typedef short s8v __attribute__((ext_vector_type(8)));
typedef float f4v __attribute__((ext_vector_type(4)));

#define BQ 32
#define TQ 512
#define DQ 1024
#define CHUNK 128
#define NCHUNK (TQ / CHUNK)
#define NTHR 256
#define NBLK_R 256

__device__ __host__ inline u16 f2bf(float f) {
    union { float f; unsigned u; } v; v.f = f;
    unsigned r = v.u + 0x7fffu + ((v.u >> 16) & 1u);  // RNE
    return (u16)(r >> 16);
}
__device__ __host__ inline float bf2f(u16 u) {
    union { unsigned u; float f; } v; v.u = ((unsigned)u) << 16;
    return v.f;
}
__device__ inline u32 packsplit(float f) {
    u16 hi = f2bf(f);
    u16 lo = f2bf(f - bf2f(hi));
    return ((u32)hi << 16) | (u32)lo;
}

// Zero hh slot 0 and the state/counter span.
__global__ void init_kernel(u32* __restrict__ z0, size_t n0,
                            u32* __restrict__ z1, size_t n1) {
    size_t i = (size_t)blockIdx.x * blockDim.x + threadIdx.x;
    size_t stride = (size_t)gridDim.x * blockDim.x;
    for (size_t idx = i; idx < n0; idx += stride) z0[idx] = 0;
    for (size_t idx = i; idx < n1; idx += stride) z1[idx] = 0;
}

// Pack W rows [0,1024) into transposed split-bf16: wpkT[n][k] = pack(W[k][n]).
// Writes coalesced; strided reads absorbed by L2/IC (one-time kernel).
__global__ void pack_w_kernel(const float* __restrict__ W, u32* __restrict__ wpkT) {
    size_t i = (size_t)blockIdx.x * blockDim.x + threadIdx.x;
    size_t stride = (size_t)gridDim.x * blockDim.x;
    const size_t NTOT = (size_t)4 * DQ * DQ;           // 4096*1024
    for (size_t idx = i; idx < NTOT; idx += stride) {
        size_t n = idx >> 10, k = idx & 1023;
        wpkT[idx] = packsplit(W[k * (4 * DQ) + n]);
    }
}

// Pack one x chunk: xpk[b][tl][k] = pack(x[b][t0+tl][k]). Fully coalesced.
__global__ void pack_x_kernel(const float* __restrict__ x, u32* __restrict__ xpk,
                              int t0) {
    size_t i = (size_t)blockIdx.x * blockDim.x + threadIdx.x;
    size_t stride = (size_t)gridDim.x * blockDim.x;
    const size_t NTOT = (size_t)BQ * CHUNK * DQ;
    for (size_t idx = i; idx < NTOT; idx += stride) {
        size_t b = idx >> 17;                  // CHUNK*DQ = 131072
        size_t r = idx & 131071;
        size_t tl = r >> 10, k = r & 1023;
        xpk[idx] = packsplit(x[((size_t)b * TQ + t0 + tl) * DQ + k]);
    }
}

// Unpack 8 packed (hi<<16|lo) u32 cols into hi/lo bf16x8 fragments.
__device__ inline void unpack_pk(uint4 A, uint4 B, s8v& hi, s8v& lo) {
    union { u32 u[4]; s8v v; } H, L;
    H.u[0] = (A.x >> 16) | (A.y & 0xffff0000u); L.u[0] = (A.x & 0xffffu) | (A.y << 16);
    H.u[1] = (A.z >> 16) | (A.w & 0xffff0000u); L.u[1] = (A.z & 0xffffu) | (A.w << 16);
    H.u[2] = (B.x >> 16) | (B.y & 0xffff0000u); L.u[2] = (B.x & 0xffffu) | (B.y << 16);
    H.u[3] = (B.z >> 16) | (B.w & 0xffff0000u); L.u[3] = (B.z & 0xffffu) | (B.w << 16);
    hi = H.v; lo = L.v;
}

// ---------------------------------------------------------------------------
// xproj GEMM v2: conversion-free staging from PACKED inputs.
// A: xpk (layer0, [B*CHUNK][DQ] packed) or hh (layer1, already packed).
// B: wpkT [4096][1024] packed transposed -> same contiguous-k staging as A.
// LDS tiles stay packed ([128][36] u32, +4 pad); unpack at fragment read
// (2 x b128 ds_read yield BOTH hi and lo fragments via unpack_pk).
// Values identical to the old f32 path => zx bit-identical.
// ---------------------------------------------------------------------------
__global__ __launch_bounds__(NTHR) void xproj_gemm_kernel(
    const u32* __restrict__ apk,        // xpk (layer0) or hh (layer1)
    const int* __restrict__ lens,
    const u32* __restrict__ wpkT,       // [4096][1024] packed
    const float* __restrict__ bias,     // [4096]
    float* __restrict__ zx,             // [B*CHUNK][4096]
    int t0, int is_l1)
{
    __shared__ u32 Asp[128][36];
    __shared__ u32 Bsp[128][36];

    const int tid = threadIdx.x;
    const int bm = blockIdx.x & 31;
    const int bn = blockIdx.x >> 5;

    const int wv = tid >> 6;
    const int wm = wv >> 1, wn = wv & 1;
    const int lane = tid & 63;
    const int frow = lane & 15;
    const int quad = lane >> 4;

    const int am = tid >> 1;            // A row 0..127 (also B col 0..127)
    const int akh = (tid & 1) * 16;     // k-half 0 / 16
    const int amg = bm * 128 + am;
    const int ab = amg >> 7;            // batch
    const int atl = amg & 127;          // t within chunk
    const int at = t0 + atl;

    bool arow_live = true;
    size_t arow;
    if (!is_l1) {
        arow = (size_t)amg * DQ;                    // xpk row
    } else {
        arow = ((size_t)(at + 1) * BQ + ab) * DQ;   // hh slot at+1 holds h_at
        arow_live = (at < lens[ab]);
    }
    const u32* bbase = wpkT + (size_t)(bn * 128 + am) * DQ;

    f4v acc[4][4];
    #pragma unroll
    for (int i = 0; i < 4; ++i)
        #pragma unroll
        for (int j = 0; j < 4; ++j) acc[i][j] = (f4v){0.f, 0.f, 0.f, 0.f};

    for (int kt = 0; kt < 32; ++kt) {
        const int k0 = kt * 32;
        {
            const u32* src = apk + arow + k0 + akh;
            #pragma unroll
            for (int j4 = 0; j4 < 4; ++j4) {
                uint4 v = ((const uint4*)src)[j4];
                if (!arow_live) { v.x = v.y = v.z = v.w = 0; }
                *(uint4*)&Asp[am][akh + 4 * j4] = v;
            }
        }
        {
            const u32* src = bbase + k0 + akh;
            #pragma unroll
            for (int j4 = 0; j4 < 4; ++j4) {
                uint4 v = ((const uint4*)src)[j4];
                *(uint4*)&Bsp[am][akh + 4 * j4] = v;
            }
        }
        __syncthreads();

        s8v ah[4], al[4], bh[4], bl[4];
        #pragma unroll
        for (int mt = 0; mt < 4; ++mt) {
            uint4 a0 = *(const uint4*)&Asp[wm * 64 + mt * 16 + frow][quad * 8];
            uint4 a1 = *(const uint4*)&Asp[wm * 64 + mt * 16 + frow][quad * 8 + 4];
            unpack_pk(a0, a1, ah[mt], al[mt]);
        }
        #pragma unroll
        for (int nt = 0; nt < 4; ++nt) {
            uint4 b0 = *(const uint4*)&Bsp[wn * 64 + nt * 16 + frow][quad * 8];
            uint4 b1 = *(const uint4*)&Bsp[wn * 64 + nt * 16 + frow][quad * 8 + 4];
            unpack_pk(b0, b1, bh[nt], bl[nt]);
        }
        #pragma unroll
        for (int mt = 0; mt < 4; ++mt)
            #pragma unroll
            for (int nt = 0; nt < 4; ++nt) {
                acc[mt][nt] = __builtin_amdgcn_mfma_f32_16x16x32_bf16(ah[mt], bh[nt], acc[mt][nt], 0, 0, 0);
                acc[mt][nt] = __builtin_amdgcn_mfma_f32_16x16x32_bf16(al[mt], bh[nt], acc[mt][nt], 0, 0, 0);
                acc[mt][nt] = __builtin_amdgcn_mfma_f32_16x16x32_bf16(ah[mt], bl[nt], acc[mt][nt], 0, 0, 0);
            }
        __syncthreads();
    }

    float bv[4];
    #pragma unroll
    for (int nt = 0; nt < 4; ++nt) bv[nt] = bias[bn * 128 + wn * 64 + nt * 16 + frow];
    #pragma unroll
    for (int mt = 0; mt < 4; ++mt) {
        #pragma unroll
        for (int nt = 0; nt < 4; ++nt) {
            int col = bn * 128 + wn * 64 + nt * 16 + frow;
            #pragma unroll
            for (int r = 0; r < 4; ++r) {
                int row = bm * 128 + wm * 64 + mt * 16 + quad * 4 + r;
                zx[(size_t)row * (4 * DQ) + col] = acc[mt][nt][r] + bv[nt];
            }
        }
    }
}

// ---------------------------------------------------------------------------
// Recurrence: VERBATIM round-0 verified kernel (753 us). 256 blocks = 2
// batch-halves (bg = blk&1, XCD parity) x 128 col-groups. h history written
// uncached (agent atomics), read with plain cached uint4 loads. Per-half
// 2-level barrier (sub 16-way -> top 8-way).
// ---------------------------------------------------------------------------
__global__ __launch_bounds__(NTHR, 1) void lstm_rec_kernel(
    const float* __restrict__ zx,   // [B*CHUNK][4096], bias folded in
    const float* __restrict__ W,    // [2048][4096], rows [1024,2048) used
    const int* __restrict__ lens,
    u32* __restrict__ hh,           // [T+1][BQ][DQ] packed hi|lo
    u32* __restrict__ subc,         // [T][2][8] stride 16
    u32* __restrict__ topc,         // [T][2] stride 16
    float* __restrict__ state_h,    // [B*DQ]
    float* __restrict__ state_c,    // [B*DQ]
    float* __restrict__ out_f32,    // layer1: d_out (else null)
    float* __restrict__ hc_out,     // layer1: d_out + B*T*DQ (h1 then c1)
    int t0, int is_last)
{
    __shared__ u16 wt[2][32][1032];
    __shared__ float red[4][16][36];

    const int tid = threadIdx.x;
    const int blk = blockIdx.x;
    const int bg = blk & 1;          // batch-half (rows bg*16 .. +16)
    const int cg = blk >> 1;         // col-group 0..127 (hcols cg*8 .. +8)
    const int grp = (blk >> 1) & 7;  // sub-barrier group within half

    for (int idx = tid; idx < 32 * 1024; idx += NTHR) {
        int n = idx & 31, k = idx >> 5;
        int c = n >> 2, g = n & 3;
        float w = W[(size_t)(DQ + k) * (4 * DQ) + g * DQ + cg * 8 + c];
        u16 wh = f2bf(w);
        wt[0][n][k] = wh;
        wt[1][n][k] = f2bf(w - bf2f(wh));
    }

    const int gb_l = tid >> 3;       // local batch 0..15
    const int gc = tid & 7;          // local hcol 0..7
    const int b_g = bg * 16 + gb_l;
    const int hcol = cg * 8 + gc;
    float c_state = 0.f, h_state = 0.f;
    int mylen = 0;
    if (tid < 128) {
        mylen = lens[b_g];
        h_state = state_h[(size_t)b_g * DQ + hcol];
        c_state = state_c[(size_t)b_g * DQ + hcol];
    }

    const int wave = tid >> 6;
    const int lane = tid & 63;
    const int frow = lane & 15;
    const int quad = lane >> 4;
    const int ksrc = wave * 256;     // K-split across 4 waves

    __syncthreads();

    const int tend = t0 + CHUNK;
    for (int t = t0; t < tend; ++t) {
        // ---- cached h-read: slot t holds h_{t-1}; fresh address => fresh data
        const u32* hp = hh + ((size_t)t * BQ + (bg * 16 + frow)) * DQ + ksrc + quad * 8;
        uint4 q[16];
        #pragma unroll
        for (int s = 0; s < 8; ++s) {
            q[2 * s]     = ((const uint4*)(hp + s * 32))[0];
            q[2 * s + 1] = ((const uint4*)(hp + s * 32))[1];
        }

        f4v acc0 = {0.f, 0.f, 0.f, 0.f};
        f4v acc1 = {0.f, 0.f, 0.f, 0.f};
        #pragma unroll
        for (int s = 0; s < 8; ++s) {
            s8v a_h, a_l;
            unpack_pk(q[2 * s], q[2 * s + 1], a_h, a_l);
            const int koff = ksrc + s * 32 + quad * 8;
            s8v b0h = *(const s8v*)&wt[0][frow][koff];
            s8v b0l = *(const s8v*)&wt[1][frow][koff];
            s8v b1h = *(const s8v*)&wt[0][16 + frow][koff];
            s8v b1l = *(const s8v*)&wt[1][16 + frow][koff];
            acc0 = __builtin_amdgcn_mfma_f32_16x16x32_bf16(a_h, b0h, acc0, 0, 0, 0);
            acc1 = __builtin_amdgcn_mfma_f32_16x16x32_bf16(a_h, b1h, acc1, 0, 0, 0);
            acc0 = __builtin_amdgcn_mfma_f32_16x16x32_bf16(a_l, b0h, acc0, 0, 0, 0);
            acc1 = __builtin_amdgcn_mfma_f32_16x16x32_bf16(a_l, b1h, acc1, 0, 0, 0);
            acc0 = __builtin_amdgcn_mfma_f32_16x16x32_bf16(a_h, b0l, acc0, 0, 0, 0);
            acc1 = __builtin_amdgcn_mfma_f32_16x16x32_bf16(a_h, b1l, acc1, 0, 0, 0);
        }
        #pragma unroll
        for (int r = 0; r < 4; ++r) {
            red[wave][quad * 4 + r][frow] = acc0[r];
            red[wave][quad * 4 + r][16 + frow] = acc1[r];
        }

        float zxv[4];
        if (tid < 128) {
            size_t base = ((size_t)b_g * CHUNK + (t - t0)) * (4 * DQ) + hcol;
            #pragma unroll
            for (int g = 0; g < 4; ++g) zxv[g] = zx[base + (size_t)g * DQ];
        }
        __syncthreads();

        if (tid < 128) {
            float z[4];
            #pragma unroll
            for (int g = 0; g < 4; ++g) {
                int n = gc * 4 + g;
                z[g] = red[0][gb_l][n] + red[1][gb_l][n] + red[2][gb_l][n] + red[3][gb_l][n]
                     + zxv[g];
            }
            float si = 1.f / (1.f + __expf(-z[0]));
            float sf = 1.f / (1.f + __expf(-(z[2] + 1.0f)));  // forget_bias
            float so = 1.f / (1.f + __expf(-z[3]));
            float cn = sf * c_state + si * tanhf(z[1]);
            float hn = so * tanhf(cn);
            bool m = (t < mylen);
            float hk = m ? hn : h_state;
            float ck = m ? cn : c_state;
            h_state = hk; c_state = ck;

            u16 hh16 = f2bf(hk);
            u16 hl16 = f2bf(hk - bf2f(hh16));
            u32 packed = ((u32)hh16 << 16) | (u32)hl16;
            __hip_atomic_store(hh + ((size_t)(t + 1) * BQ + b_g) * DQ + hcol,
                               packed, __ATOMIC_RELAXED, __HIP_MEMORY_SCOPE_AGENT);

            if (is_last) {
                float ho = m ? hn : 0.f;
                out_f32[((size_t)b_g * TQ + t) * DQ + hcol] = ho;
            }
        }

        // ---- drain h store, then per-half 2-level barrier ----
        asm volatile("s_waitcnt vmcnt(0)" ::: "memory");
        __syncthreads();
        if (t < tend - 1) {
            if (tid == 0) {
                u32* sc = &subc[((t * 2 + bg) * 8 + grp) * 16];
                u32* tc = &topc[(t * 2 + bg) * 16];
                u32 old = atomicAdd(sc, 1u);
                if (old == 15) atomicAdd(tc, 1u);
                while (__hip_atomic_load(tc, __ATOMIC_RELAXED,
                                         __HIP_MEMORY_SCOPE_AGENT) < 8) { }
            }
            __syncthreads();
        }
    }

    if (tid < 128) {
        state_h[(size_t)b_g * DQ + hcol] = h_state;
        state_c[(size_t)b_g * DQ + hcol] = c_state;
        if (is_last && tend == TQ) {
            hc_out[(size_t)b_g * DQ + hcol] = h_state;
            hc_out[(size_t)BQ * DQ + (size_t)b_g * DQ + hcol] = c_state;
        }
    }
}

extern "C" void kernel_launch(void* const* d_in, const int* in_sizes, int n_in,
                              void* d_out, int out_size, void* d_ws, size_t ws_size,
                              hipStream_t stream) {
    const float* x    = (const float*)d_in[0];
    const int*   lens = (const int*)d_in[1];
    const float* W0   = (const float*)d_in[2];
    const float* b0   = (const float*)d_in[3];
    const float* W1   = (const float*)d_in[4];
    const float* b1   = (const float*)d_in[5];
    float* out = (float*)d_out;

    const size_t N   = (size_t)BQ * TQ * DQ;           // 16,777,216
    const size_t ZXN = (size_t)BQ * CHUNK * 4 * DQ;    // 16,777,216 f32
    const size_t HD  = (size_t)BQ * DQ;                // 32768
    const size_t WPK = (size_t)4 * DQ * DQ;            // 4,194,304 u32
    const size_t XPK = (size_t)BQ * CHUNK * DQ;        // 4,194,304 u32

    float* zx  = (float*)d_ws;
    u32* hh    = (u32*)(zx + ZXN);                     // [T+1][BQ][DQ]
    // zero span: states + counters (contiguous)
    float* sh0 = (float*)(hh + (size_t)(TQ + 1) * HD);
    float* sc0 = sh0 + HD;
    float* sh1 = sc0 + HD;
    float* sc1 = sh1 + HD;
    u32* sub0  = (u32*)(sc1 + HD);
    u32* top0  = sub0 + (size_t)TQ * 2 * 8 * 16;
    u32* sub1  = top0 + (size_t)TQ * 2 * 16;
    u32* top1  = sub1 + (size_t)TQ * 2 * 8 * 16;
    u32* zend  = top1 + (size_t)TQ * 2 * 16;
    const size_t nzero = (size_t)(zend - (u32*)sh0);
    u32* wpk0  = zend;                                 // [4096][1024] packed
    u32* wpk1  = wpk0 + WPK;
    u32* xpk   = wpk1 + WPK;                           // [B][CHUNK][DQ] packed

    // zero hh slot 0 (h_{-1} = 0) and the state/counter span
    init_kernel<<<256, 256, 0, stream>>>(hh, HD, (u32*)sh0, nzero);
    // one-time weight packing (rows [0,1024), transposed, split-bf16)
    pack_w_kernel<<<2048, 256, 0, stream>>>(W0, wpk0);
    pack_w_kernel<<<2048, 256, 0, stream>>>(W1, wpk1);

    for (int c = 0; c < NCHUNK; ++c) {
        int t0 = c * CHUNK;
        pack_x_kernel<<<2048, 256, 0, stream>>>(x, xpk, t0);
        xproj_gemm_kernel<<<1024, NTHR, 0, stream>>>(xpk, lens, wpk0, b0, zx, t0, 0);
        lstm_rec_kernel<<<NBLK_R, NTHR, 0, stream>>>(
            zx, W0, lens, hh, sub0, top0, sh0, sc0,
            nullptr, nullptr, t0, 0);
    }
    for (int c = 0; c < NCHUNK; ++c) {
        int t0 = c * CHUNK;
        xproj_gemm_kernel<<<1024, NTHR, 0, stream>>>(hh, lens, wpk1, b1, zx, t0, 1);
        lstm_rec_kernel<<<NBLK_R, NTHR, 0, stream>>>(
            zx, W1, lens, hh, sub1, top1, sh1, sc1,
            out, out + N, t0, 1);
    }
}